// Round 4
// baseline (9641.145 us; speedup 1.0000x reference)
//
#include <hip/hip_runtime.h>

#define T_STEPS 512
#define D_IN    32
#define H       64
#define NB      4     // batch elements per block

// ---- DPP cross-lane add: sum over the 4 lanes of each quad (chunk id = lane&3) ----
template<int CTRL>
__device__ __forceinline__ float dpp_add(float v) {
    int m = __builtin_amdgcn_update_dpp(0, __float_as_int(v), CTRL, 0xf, 0xf, true);
    return v + __int_as_float(m);
}
__device__ __forceinline__ float red4(float v) {
    v = dpp_add<0xB1>(v);   // quad_perm [1,0,3,2] : + lane^1
    v = dpp_add<0x4E>(v);   // quad_perm [2,3,0,1] : + lane^2
    return v;
}

__device__ __forceinline__ float sigf(float x) {
    return 1.0f / (1.0f + __expf(-x));
}
__device__ __forceinline__ float tanhf_(float x) {
    float e = __expf(2.0f * x);
    return 1.0f - 2.0f / (e + 1.0f);
}

__global__ __launch_bounds__(512, 2)
void lstm2_fused(const float* __restrict__ x,
                 const float* __restrict__ Wih0, const float* __restrict__ Whh0,
                 const float* __restrict__ bih0, const float* __restrict__ bhh0,
                 const float* __restrict__ Wih1, const float* __restrict__ Whh1,
                 const float* __restrict__ bih1, const float* __restrict__ bhh1,
                 const float* __restrict__ Wfc,  const float* __restrict__ bfc,
                 float* __restrict__ out)
{
    // L0 input: vin[b] = { x_t (32) , h0 (64) } contiguous.
    //   chunk c reads float4 at 24c+4q -> bank-quads {0,24,16,8}+4q mod 32: conflict-free
    __shared__ __align__(16) float vin[NB][96];
    // L1 input: u1[b][c][36] = chunk c holds k in [32c, 32c+32), +4 pad floats.
    //   float4 at [c][4q] -> bank-quads {0,4,8,12}+4q mod 32: conflict-free
    __shared__ __align__(16) float u1[NB][4][36];
    __shared__ __align__(16) float g0buf[NB][256];
    __shared__ __align__(16) float g1buf[NB][256];

    const int tid  = threadIdx.x;
    const int b0   = blockIdx.x * NB;
    // waves 0-3 = L0, waves 4-7 = L1 -> each SIMD gets one of each (round-robin)
    const bool isL0 = tid < 256;
    const int t    = isL0 ? tid : tid - 256;
    const int c    = t & 3;          // K-chunk id
    const int rg   = t >> 2;         // row-group 0..63 (4 rows each)
    const int r0   = 4 * rg;

    // ---- per-thread weights: 4 rows x 1 chunk (L0: 96 floats, L1: 128) ----
    // layout: wq[q][rr] as float4
    float4 wq0[6][4];    // L0 uses [6][4]
    float4 wq1[8][4];    // L1 uses [8][4]
    if (isL0) {
#pragma unroll
        for (int q = 0; q < 6; ++q)
#pragma unroll
            for (int rr = 0; rr < 4; ++rr) {
                int r = r0 + rr;
                float tv[4];
#pragma unroll
                for (int e = 0; e < 4; ++e) {
                    int k = 24 * c + 4 * q + e;
                    tv[e] = (k < 32) ? Wih0[r * D_IN + k] : Whh0[r * H + (k - 32)];
                }
                wq0[q][rr] = make_float4(tv[0], tv[1], tv[2], tv[3]);
            }
    } else {
#pragma unroll
        for (int q = 0; q < 8; ++q)
#pragma unroll
            for (int rr = 0; rr < 4; ++rr) {
                int r = r0 + rr;
                float tv[4];
#pragma unroll
                for (int e = 0; e < 4; ++e) {
                    int k = 32 * c + 4 * q + e;
                    tv[e] = (k < 64) ? Wih1[r * H + k] : Whh1[r * H + (k - 64)];
                }
                wq1[q][rr] = make_float4(tv[0], tv[1], tv[2], tv[3]);
            }
    }

    // ---- phase-C state owners ----
    // h0 states: threads [0,256); h1 states: threads [256,512)
    // x staging: threads [128,256)
    const int jst = tid & 63;
    const int bst = (tid >> 6) & 3;
    float bi, bff, bg, bo, cst = 0.f;
    if (isL0) {
        bi  = bih0[jst]       + bhh0[jst];
        bff = bih0[64 + jst]  + bhh0[64 + jst];
        bg  = bih0[128 + jst] + bhh0[128 + jst];
        bo  = bih0[192 + jst] + bhh0[192 + jst];
    } else {
        bi  = bih1[jst]       + bhh1[jst];
        bff = bih1[64 + jst]  + bhh1[64 + jst];
        bg  = bih1[128 + jst] + bhh1[128 + jst];
        bo  = bih1[192 + jst] + bhh1[192 + jst];
    }

    // x-prefetch base pointer (threads 128..255)
    const bool isx = (tid >= 128 && tid < 256);
    const float* xp = nullptr;
    if (isx) {
        int t2 = tid - 128, b = t2 >> 5, k = t2 & 31;
        xp = x + (size_t)(b0 + b) * T_STEPS * D_IN + k;
    }

    // ---- init: zero h-state LDS, stage x_0 ----
    if (tid < 256) vin[tid >> 6][32 + (tid & 63)] = 0.f;
    {   // zero u1 (576 floats incl. pads)
        ((float*)u1)[tid] = 0.f;
        if (tid < 64) ((float*)u1)[512 + tid] = 0.f;
    }
    if (isx) {
        int t2 = tid - 128, b = t2 >> 5, k = t2 & 31;
        vin[b][k] = xp[0];
    }
    __syncthreads();

    for (int it = 0; it <= T_STEPS; ++it) {
        // register-prefetch x_{it+1}
        float xpre = 0.f;
        const bool havex = isx && (it + 1 < T_STEPS);
        if (havex) xpre = xp[(size_t)(it + 1) * D_IN];

        // ---- phase A: chunked gate matvecs, q-outer / rr-mid / b-inner ----
        float acc[4][NB];
#pragma unroll
        for (int rr = 0; rr < 4; ++rr)
#pragma unroll
            for (int b = 0; b < NB; ++b) acc[rr][b] = 0.f;

        if (isL0) {
            if (it < T_STEPS) {
#pragma unroll
                for (int q = 0; q < 6; ++q) {
                    float4 v0 = *(const float4*)&vin[0][24 * c + 4 * q];
                    float4 v1 = *(const float4*)&vin[1][24 * c + 4 * q];
                    float4 v2 = *(const float4*)&vin[2][24 * c + 4 * q];
                    float4 v3 = *(const float4*)&vin[3][24 * c + 4 * q];
#pragma unroll
                    for (int rr = 0; rr < 4; ++rr) {
                        float4 w = wq0[q][rr];
                        acc[rr][0] = fmaf(w.x, v0.x, acc[rr][0]);
                        acc[rr][0] = fmaf(w.y, v0.y, acc[rr][0]);
                        acc[rr][0] = fmaf(w.z, v0.z, acc[rr][0]);
                        acc[rr][0] = fmaf(w.w, v0.w, acc[rr][0]);
                        acc[rr][1] = fmaf(w.x, v1.x, acc[rr][1]);
                        acc[rr][1] = fmaf(w.y, v1.y, acc[rr][1]);
                        acc[rr][1] = fmaf(w.z, v1.z, acc[rr][1]);
                        acc[rr][1] = fmaf(w.w, v1.w, acc[rr][1]);
                        acc[rr][2] = fmaf(w.x, v2.x, acc[rr][2]);
                        acc[rr][2] = fmaf(w.y, v2.y, acc[rr][2]);
                        acc[rr][2] = fmaf(w.z, v2.z, acc[rr][2]);
                        acc[rr][2] = fmaf(w.w, v2.w, acc[rr][2]);
                        acc[rr][3] = fmaf(w.x, v3.x, acc[rr][3]);
                        acc[rr][3] = fmaf(w.y, v3.y, acc[rr][3]);
                        acc[rr][3] = fmaf(w.z, v3.z, acc[rr][3]);
                        acc[rr][3] = fmaf(w.w, v3.w, acc[rr][3]);
                    }
                }
#pragma unroll
                for (int b = 0; b < NB; ++b) {
                    float a0 = red4(acc[0][b]);
                    float a1 = red4(acc[1][b]);
                    float a2 = red4(acc[2][b]);
                    float a3 = red4(acc[3][b]);
                    if (c == 0)
                        *(float4*)&g0buf[b][r0] = make_float4(a0, a1, a2, a3);
                }
            }
        } else {
            if (it >= 1) {
#pragma unroll
                for (int q = 0; q < 8; ++q) {
                    float4 v0 = *(const float4*)&u1[0][c][4 * q];
                    float4 v1 = *(const float4*)&u1[1][c][4 * q];
                    float4 v2 = *(const float4*)&u1[2][c][4 * q];
                    float4 v3 = *(const float4*)&u1[3][c][4 * q];
#pragma unroll
                    for (int rr = 0; rr < 4; ++rr) {
                        float4 w = wq1[q][rr];
                        acc[rr][0] = fmaf(w.x, v0.x, acc[rr][0]);
                        acc[rr][0] = fmaf(w.y, v0.y, acc[rr][0]);
                        acc[rr][0] = fmaf(w.z, v0.z, acc[rr][0]);
                        acc[rr][0] = fmaf(w.w, v0.w, acc[rr][0]);
                        acc[rr][1] = fmaf(w.x, v1.x, acc[rr][1]);
                        acc[rr][1] = fmaf(w.y, v1.y, acc[rr][1]);
                        acc[rr][1] = fmaf(w.z, v1.z, acc[rr][1]);
                        acc[rr][1] = fmaf(w.w, v1.w, acc[rr][1]);
                        acc[rr][2] = fmaf(w.x, v2.x, acc[rr][2]);
                        acc[rr][2] = fmaf(w.y, v2.y, acc[rr][2]);
                        acc[rr][2] = fmaf(w.z, v2.z, acc[rr][2]);
                        acc[rr][2] = fmaf(w.w, v2.w, acc[rr][2]);
                        acc[rr][3] = fmaf(w.x, v3.x, acc[rr][3]);
                        acc[rr][3] = fmaf(w.y, v3.y, acc[rr][3]);
                        acc[rr][3] = fmaf(w.z, v3.z, acc[rr][3]);
                        acc[rr][3] = fmaf(w.w, v3.w, acc[rr][3]);
                    }
                }
#pragma unroll
                for (int b = 0; b < NB; ++b) {
                    float a0 = red4(acc[0][b]);
                    float a1 = red4(acc[1][b]);
                    float a2 = red4(acc[2][b]);
                    float a3 = red4(acc[3][b]);
                    if (c == 0)
                        *(float4*)&g1buf[b][r0] = make_float4(a0, a1, a2, a3);
                }
            }
        }
        __syncthreads();

        // ---- phase C: cell updates + x commit ----
        if (isL0) {
            if (it < T_STEPS) {
                float gi = g0buf[bst][jst]       + bi;
                float gf = g0buf[bst][64 + jst]  + bff;
                float gg = g0buf[bst][128 + jst] + bg;
                float go = g0buf[bst][192 + jst] + bo;
                float cc = sigf(gf) * cst + sigf(gi) * tanhf_(gg);
                cst = cc;
                float hh = sigf(go) * tanhf_(cc);
                vin[bst][32 + jst]          = hh;   // L0's next-step input
                u1[bst][jst >> 5][jst & 31] = hh;   // L1 input chunk (k = jst)
            }
        } else {
            if (it >= 1) {
                float gi = g1buf[bst][jst]       + bi;
                float gf = g1buf[bst][64 + jst]  + bff;
                float gg = g1buf[bst][128 + jst] + bg;
                float go = g1buf[bst][192 + jst] + bo;
                float cc = sigf(gf) * cst + sigf(gi) * tanhf_(gg);
                cst = cc;
                float hh = sigf(go) * tanhf_(cc);
                u1[bst][2 + (jst >> 5)][jst & 31] = hh;  // k = 64 + jst
            }
        }
        if (havex) {
            int t2 = tid - 128, b = t2 >> 5, k = t2 & 31;
            vin[b][k] = xpre;
        }
        __syncthreads();
    }

    // ---- final FC on h1[T-1] ----
    if (tid < NB) {
        float s = bfc[0];
#pragma unroll
        for (int k = 0; k < H; ++k)
            s += u1[tid][2 + (k >> 5)][k & 31] * Wfc[k];
        out[b0 + tid] = s;
    }
}

extern "C" void kernel_launch(void* const* d_in, const int* in_sizes, int n_in,
                              void* d_out, int out_size, void* d_ws, size_t ws_size,
                              hipStream_t stream) {
    const float* x    = (const float*)d_in[0];
    const float* Wih0 = (const float*)d_in[1];
    const float* Whh0 = (const float*)d_in[2];
    const float* bih0 = (const float*)d_in[3];
    const float* bhh0 = (const float*)d_in[4];
    const float* Wih1 = (const float*)d_in[5];
    const float* Whh1 = (const float*)d_in[6];
    const float* bih1 = (const float*)d_in[7];
    const float* bhh1 = (const float*)d_in[8];
    const float* Wfc  = (const float*)d_in[9];
    const float* bfc  = (const float*)d_in[10];
    float* out = (float*)d_out;

    const int B = out_size;            // 1024
    dim3 grid(B / NB), block(512);
    hipLaunchKernelGGL(lstm2_fused, grid, block, 0, stream,
                       x, Wih0, Whh0, bih0, bhh0,
                       Wih1, Whh1, bih1, bhh1, Wfc, bfc, out);
}

// Round 5
// 1062.077 us; speedup vs baseline: 9.0776x; 9.0776x over previous
//
#include <hip/hip_runtime.h>

#define T_STEPS 512
#define D_IN    32
#define H       64
#define NB      4     // batch elements per block

// ---- DPP cross-lane add: sum over the 4 lanes of each quad (chunk id = lane&3) ----
template<int CTRL>
__device__ __forceinline__ float dpp_add(float v) {
    int m = __builtin_amdgcn_update_dpp(0, __float_as_int(v), CTRL, 0xf, 0xf, true);
    return v + __int_as_float(m);
}
__device__ __forceinline__ float red4(float v) {
    v = dpp_add<0xB1>(v);   // quad_perm [1,0,3,2] : + lane^1
    v = dpp_add<0x4E>(v);   // quad_perm [2,3,0,1] : + lane^2
    return v;
}

__device__ __forceinline__ float sigf(float x) {
    return 1.0f / (1.0f + __expf(-x));
}
__device__ __forceinline__ float tanhf_(float x) {
    float e = __expf(2.0f * x);
    return 1.0f - 2.0f / (e + 1.0f);
}

__global__ __launch_bounds__(512, 2)
void lstm2_fused(const float* __restrict__ x,
                 const float* __restrict__ Wih0, const float* __restrict__ Whh0,
                 const float* __restrict__ bih0, const float* __restrict__ bhh0,
                 const float* __restrict__ Wih1, const float* __restrict__ Whh1,
                 const float* __restrict__ bih1, const float* __restrict__ bhh1,
                 const float* __restrict__ Wfc,  const float* __restrict__ bfc,
                 float* __restrict__ out)
{
    // L0 input: vin[b] = { x_t (32) , h0 (64) } contiguous.
    //   chunk c reads float4 at 24c+4q -> bank-quads {0,24,16,8}+4q mod 32: conflict-free
    __shared__ __align__(16) float vin[NB][96];
    // L1 input: u1[b][c][36] = chunk c holds k in [32c, 32c+32), +4 pad floats.
    //   float4 at [c][4q] -> bank-quads {0,4,8,12}+4q mod 32: conflict-free
    __shared__ __align__(16) float u1[NB][4][36];
    __shared__ __align__(16) float g0buf[NB][256];
    __shared__ __align__(16) float g1buf[NB][256];

    const int tid  = threadIdx.x;
    const int b0   = blockIdx.x * NB;
    // waves 0-3 = L0, waves 4-7 = L1 -> each SIMD gets one of each (round-robin)
    const bool isL0 = tid < 256;
    const int t    = isL0 ? tid : tid - 256;
    const int c    = t & 3;          // K-chunk id
    const int rg   = t >> 2;         // row-group 0..63 (4 rows each)
    const int r0   = 4 * rg;

    // ---- per-thread weights: 4 rows x 1 chunk, ONE shared array (128 floats).
    //      L0 uses q=0..5 (chunk=24 of K=96); L1 uses q=0..7 (chunk=32 of K=128).
    //      Single array keeps total declared live set under the 256-reg budget
    //      (two separate arrays -> 224 live floats -> scratch spill, R3/R4). ----
    float4 wq[8][4];
    if (isL0) {
#pragma unroll
        for (int q = 0; q < 6; ++q)
#pragma unroll
            for (int rr = 0; rr < 4; ++rr) {
                int r = r0 + rr;
                float tv[4];
#pragma unroll
                for (int e = 0; e < 4; ++e) {
                    int k = 24 * c + 4 * q + e;
                    tv[e] = (k < 32) ? Wih0[r * D_IN + k] : Whh0[r * H + (k - 32)];
                }
                wq[q][rr] = make_float4(tv[0], tv[1], tv[2], tv[3]);
            }
    } else {
#pragma unroll
        for (int q = 0; q < 8; ++q)
#pragma unroll
            for (int rr = 0; rr < 4; ++rr) {
                int r = r0 + rr;
                float tv[4];
#pragma unroll
                for (int e = 0; e < 4; ++e) {
                    int k = 32 * c + 4 * q + e;
                    tv[e] = (k < 64) ? Wih1[r * H + k] : Whh1[r * H + (k - 64)];
                }
                wq[q][rr] = make_float4(tv[0], tv[1], tv[2], tv[3]);
            }
    }

    // ---- phase-C state owners ----
    const int jst = tid & 63;
    const int bst = (tid >> 6) & 3;
    float bi, bff, bg, bo, cst = 0.f;
    if (isL0) {
        bi  = bih0[jst]       + bhh0[jst];
        bff = bih0[64 + jst]  + bhh0[64 + jst];
        bg  = bih0[128 + jst] + bhh0[128 + jst];
        bo  = bih0[192 + jst] + bhh0[192 + jst];
    } else {
        bi  = bih1[jst]       + bhh1[jst];
        bff = bih1[64 + jst]  + bhh1[64 + jst];
        bg  = bih1[128 + jst] + bhh1[128 + jst];
        bo  = bih1[192 + jst] + bhh1[192 + jst];
    }

    // x-prefetch base pointer (threads 128..255)
    const bool isx = (tid >= 128 && tid < 256);
    const float* xp = nullptr;
    if (isx) {
        int t2 = tid - 128, b = t2 >> 5, k = t2 & 31;
        xp = x + (size_t)(b0 + b) * T_STEPS * D_IN + k;
    }

    // ---- init: zero h-state LDS, stage x_0 ----
    if (tid < 256) vin[tid >> 6][32 + (tid & 63)] = 0.f;
    {   // zero u1 (576 floats incl. pads)
        ((float*)u1)[tid] = 0.f;
        if (tid < 64) ((float*)u1)[512 + tid] = 0.f;
    }
    if (isx) {
        int t2 = tid - 128, b = t2 >> 5, k = t2 & 31;
        vin[b][k] = xp[0];
    }
    __syncthreads();

    for (int it = 0; it <= T_STEPS; ++it) {
        // register-prefetch x_{it+1}
        float xpre = 0.f;
        const bool havex = isx && (it + 1 < T_STEPS);
        if (havex) xpre = xp[(size_t)(it + 1) * D_IN];

        // ---- phase A: chunked gate matvecs, q-outer / rr-mid / b-inner ----
        float acc[4][NB];
#pragma unroll
        for (int rr = 0; rr < 4; ++rr)
#pragma unroll
            for (int b = 0; b < NB; ++b) acc[rr][b] = 0.f;

        if (isL0) {
            if (it < T_STEPS) {
#pragma unroll
                for (int q = 0; q < 6; ++q) {
                    float4 v0 = *(const float4*)&vin[0][24 * c + 4 * q];
                    float4 v1 = *(const float4*)&vin[1][24 * c + 4 * q];
                    float4 v2 = *(const float4*)&vin[2][24 * c + 4 * q];
                    float4 v3 = *(const float4*)&vin[3][24 * c + 4 * q];
#pragma unroll
                    for (int rr = 0; rr < 4; ++rr) {
                        float4 w = wq[q][rr];
                        acc[rr][0] = fmaf(w.x, v0.x, acc[rr][0]);
                        acc[rr][0] = fmaf(w.y, v0.y, acc[rr][0]);
                        acc[rr][0] = fmaf(w.z, v0.z, acc[rr][0]);
                        acc[rr][0] = fmaf(w.w, v0.w, acc[rr][0]);
                        acc[rr][1] = fmaf(w.x, v1.x, acc[rr][1]);
                        acc[rr][1] = fmaf(w.y, v1.y, acc[rr][1]);
                        acc[rr][1] = fmaf(w.z, v1.z, acc[rr][1]);
                        acc[rr][1] = fmaf(w.w, v1.w, acc[rr][1]);
                        acc[rr][2] = fmaf(w.x, v2.x, acc[rr][2]);
                        acc[rr][2] = fmaf(w.y, v2.y, acc[rr][2]);
                        acc[rr][2] = fmaf(w.z, v2.z, acc[rr][2]);
                        acc[rr][2] = fmaf(w.w, v2.w, acc[rr][2]);
                        acc[rr][3] = fmaf(w.x, v3.x, acc[rr][3]);
                        acc[rr][3] = fmaf(w.y, v3.y, acc[rr][3]);
                        acc[rr][3] = fmaf(w.z, v3.z, acc[rr][3]);
                        acc[rr][3] = fmaf(w.w, v3.w, acc[rr][3]);
                    }
                }
#pragma unroll
                for (int b = 0; b < NB; ++b) {
                    float a0 = red4(acc[0][b]);
                    float a1 = red4(acc[1][b]);
                    float a2 = red4(acc[2][b]);
                    float a3 = red4(acc[3][b]);
                    if (c == 0)
                        *(float4*)&g0buf[b][r0] = make_float4(a0, a1, a2, a3);
                }
            }
        } else {
            if (it >= 1) {
#pragma unroll
                for (int q = 0; q < 8; ++q) {
                    float4 v0 = *(const float4*)&u1[0][c][4 * q];
                    float4 v1 = *(const float4*)&u1[1][c][4 * q];
                    float4 v2 = *(const float4*)&u1[2][c][4 * q];
                    float4 v3 = *(const float4*)&u1[3][c][4 * q];
#pragma unroll
                    for (int rr = 0; rr < 4; ++rr) {
                        float4 w = wq[q][rr];
                        acc[rr][0] = fmaf(w.x, v0.x, acc[rr][0]);
                        acc[rr][0] = fmaf(w.y, v0.y, acc[rr][0]);
                        acc[rr][0] = fmaf(w.z, v0.z, acc[rr][0]);
                        acc[rr][0] = fmaf(w.w, v0.w, acc[rr][0]);
                        acc[rr][1] = fmaf(w.x, v1.x, acc[rr][1]);
                        acc[rr][1] = fmaf(w.y, v1.y, acc[rr][1]);
                        acc[rr][1] = fmaf(w.z, v1.z, acc[rr][1]);
                        acc[rr][1] = fmaf(w.w, v1.w, acc[rr][1]);
                        acc[rr][2] = fmaf(w.x, v2.x, acc[rr][2]);
                        acc[rr][2] = fmaf(w.y, v2.y, acc[rr][2]);
                        acc[rr][2] = fmaf(w.z, v2.z, acc[rr][2]);
                        acc[rr][2] = fmaf(w.w, v2.w, acc[rr][2]);
                        acc[rr][3] = fmaf(w.x, v3.x, acc[rr][3]);
                        acc[rr][3] = fmaf(w.y, v3.y, acc[rr][3]);
                        acc[rr][3] = fmaf(w.z, v3.z, acc[rr][3]);
                        acc[rr][3] = fmaf(w.w, v3.w, acc[rr][3]);
                    }
                }
#pragma unroll
                for (int b = 0; b < NB; ++b) {
                    float a0 = red4(acc[0][b]);
                    float a1 = red4(acc[1][b]);
                    float a2 = red4(acc[2][b]);
                    float a3 = red4(acc[3][b]);
                    if (c == 0)
                        *(float4*)&g1buf[b][r0] = make_float4(a0, a1, a2, a3);
                }
            }
        }
        __syncthreads();

        // ---- phase C: cell updates + x commit ----
        if (isL0) {
            if (it < T_STEPS) {
                float gi = g0buf[bst][jst]       + bi;
                float gf = g0buf[bst][64 + jst]  + bff;
                float gg = g0buf[bst][128 + jst] + bg;
                float go = g0buf[bst][192 + jst] + bo;
                float cc = sigf(gf) * cst + sigf(gi) * tanhf_(gg);
                cst = cc;
                float hh = sigf(go) * tanhf_(cc);
                vin[bst][32 + jst]          = hh;   // L0's next-step input
                u1[bst][jst >> 5][jst & 31] = hh;   // L1 input chunk (k = jst)
            }
        } else {
            if (it >= 1) {
                float gi = g1buf[bst][jst]       + bi;
                float gf = g1buf[bst][64 + jst]  + bff;
                float gg = g1buf[bst][128 + jst] + bg;
                float go = g1buf[bst][192 + jst] + bo;
                float cc = sigf(gf) * cst + sigf(gi) * tanhf_(gg);
                cst = cc;
                float hh = sigf(go) * tanhf_(cc);
                u1[bst][2 + (jst >> 5)][jst & 31] = hh;  // k = 64 + jst
            }
        }
        if (havex) {
            int t2 = tid - 128, b = t2 >> 5, k = t2 & 31;
            vin[b][k] = xpre;
        }
        __syncthreads();
    }

    // ---- final FC on h1[T-1] ----
    if (tid < NB) {
        float s = bfc[0];
#pragma unroll
        for (int k = 0; k < H; ++k)
            s += u1[tid][2 + (k >> 5)][k & 31] * Wfc[k];
        out[b0 + tid] = s;
    }
}

extern "C" void kernel_launch(void* const* d_in, const int* in_sizes, int n_in,
                              void* d_out, int out_size, void* d_ws, size_t ws_size,
                              hipStream_t stream) {
    const float* x    = (const float*)d_in[0];
    const float* Wih0 = (const float*)d_in[1];
    const float* Whh0 = (const float*)d_in[2];
    const float* bih0 = (const float*)d_in[3];
    const float* bhh0 = (const float*)d_in[4];
    const float* Wih1 = (const float*)d_in[5];
    const float* Whh1 = (const float*)d_in[6];
    const float* bih1 = (const float*)d_in[7];
    const float* bhh1 = (const float*)d_in[8];
    const float* Wfc  = (const float*)d_in[9];
    const float* bfc  = (const float*)d_in[10];
    float* out = (float*)d_out;

    const int B = out_size;            // 1024
    dim3 grid(B / NB), block(512);
    hipLaunchKernelGGL(lstm2_fused, grid, block, 0, stream,
                       x, Wih0, Whh0, bih0, bhh0,
                       Wih1, Whh1, bih1, bhh1, Wfc, bfc, out);
}